// Round 2
// baseline (1402.608 us; speedup 1.0000x reference)
//
#include <hip/hip_runtime.h>
#include <cstddef>

// DFMNET: 2-layer LSTM (B=2048,T=256,I=64,H=128) + 6-layer KDN.
// Round 7: r6's "+v" pin left VGPR_Count=128 -> weights sat in AGPRs with
// per-use v_accvgpr moves (~400 extra VALU/step/wave) and the r6 ask (176+128
// = 304 regs/thread) was over the 256/thread tier anyway. Fix the arithmetic:
//   - WPARK grows to 16 frags (cell1 kc0..3): LDS = 160768 B (fits 160 KiB,
//     still 1 block/CU).
//   - Resident = exactly 40 frags (cell1 kc4,5 + all of cell2) = 160 AGPRs,
//     pinned with the AGPR constraint "+a" (gfx950 MFMA reads A/B directly
//     from AGPR - zero per-use moves). 160 AGPR + <=96 arch VGPR = 256 =
//     the 2-waves/EU tier exactly.
// Watch: FETCH_SIZE >> 70MB or regression => scratch spill => drop to 36.

typedef __attribute__((ext_vector_type(8))) short short8;
typedef __attribute__((ext_vector_type(4))) float float4v;

#define OFF_Y  ((size_t)0)
#define OFF_H2 ((size_t)2048*64)
#define OFF_R  ((size_t)2048*192)

// ---- d_ws byte offsets (all 64-aligned) ----
#define WS_FLAGS   0
#define WS_W1I     64           // [512][64]  bf16
#define WS_W1H     65600        // [512][128] bf16
#define WS_W2I     196672      // [512][128] bf16
#define WS_W2H     327744      // [512][128] bf16
#define WS_WK0     458816      // [128][192] bf16
#define WS_WK1     507968      // [128][128] bf16
#define WS_WK2     540736
#define WS_WK3     573504
#define WS_WK4     606272
#define WS_WK5     639040      // [64][128] bf16
#define WS_B1      655424      // [512] f32 (bih1+bhh1)
#define WS_B2      657472      // [512] f32
#define WS_BK0     659520      // [128] f32
#define WS_BK1     660032
#define WS_BK2     660544
#define WS_BK3     661056
#define WS_BK4     661568
#define WS_BK5     662080      // [64] f32
#define WS_RB      662336      // [2048][192] bf16

__device__ __forceinline__ float bf2f(unsigned short u){
  union { unsigned int i; float f; } c; c.i = ((unsigned int)u) << 16; return c.f;
}
__device__ __forceinline__ unsigned short f2bf(float f){
  union { float f; unsigned int i; } c; c.f = f;
  unsigned int x = c.i;
  unsigned int r = (x + 0x7FFFu + ((x >> 16) & 1u)) >> 16;   // RNE
  return (unsigned short)r;
}
__device__ __forceinline__ float sig_(float x){ return 1.0f/(1.0f + __expf(-x)); }
__device__ __forceinline__ float tanh_(float x){ return 2.0f/(1.0f + __expf(-2.0f*x)) - 1.0f; }

#define MFMA16(a,b,c) __builtin_amdgcn_mfma_f32_16x16x32_bf16((a),(b),(c),0,0,0)

__device__ __forceinline__ unsigned int ldx2(const void* x, size_t off, int f32){
  if (f32){
    const float* p = (const float*)x + off;
    return (unsigned int)f2bf(p[0]) | ((unsigned int)f2bf(p[1]) << 16);
  }
  return *(const unsigned int*)((const unsigned short*)x + off);
}
__device__ __forceinline__ float ld1f(const void* p, int i, int f32){
  if (f32) return ((const float*)p)[i];
  return bf2f(((const unsigned short*)p)[i]);
}
__device__ __forceinline__ void st1(void* o, size_t off, float v, int f32){
  if (f32) ((float*)o)[off] = v;
  else     ((unsigned short*)o)[off] = f2bf(v);
}

// ---------------------------------------------------------------------------
// dtype probe: flags[a]=1 iff array a is fp32 (verified round 3)
// ---------------------------------------------------------------------------
__global__ void probe_kernel(const void* x,
                             const void* w1i, const void* w1h,
                             const void* w2i, const void* w2h,
                             const void* k0, const void* k1, const void* k2,
                             const void* k3, const void* k4, const void* k5,
                             int* flags)
{
  const void* arrs[11] = {x, w1i, w1h, w2i, w2h, k0, k1, k2, k3, k4, k5};
  const int lane = threadIdx.x & 63;
  for (int a = 0; a < 11; a++){
    const unsigned short* p = (const unsigned short*)arrs[a];
    int bad = 0;
    #pragma unroll
    for (int j = 0; j < 8; j++){
      float v = bf2f(p[lane*8 + j]);
      if (!(v > -1e3f && v < 1e3f)) bad = 1;
    }
    unsigned long long m = __ballot(bad);
    if (lane == 0) flags[a] = (m != 0ull) ? 1 : 0;
  }
}

// ---------------------------------------------------------------------------
// convert: weights -> bf16 in ws; bias sums -> f32 in ws
// ---------------------------------------------------------------------------
__device__ __forceinline__ void conv_range(const void* src, unsigned short* dst,
                                           int lo, int n, int f32, int t){
  int hi = lo + 4096; if (hi > n) hi = n;
  for (int i = lo + t; i < hi; i += 256)
    dst[i] = f32 ? f2bf(((const float*)src)[i]) : ((const unsigned short*)src)[i];
}

__global__ void convert_kernel(const void* w1i, const void* w1h,
                               const void* w2i, const void* w2h,
                               const void* k0, const void* k1, const void* k2,
                               const void* k3, const void* k4, const void* k5,
                               const void* bi1, const void* bh1,
                               const void* bi2, const void* bh2,
                               const void* bb0, const void* bb1, const void* bb2,
                               const void* bb3, const void* bb4, const void* bb5,
                               char* ws)
{
  const int* flags = (const int*)(ws + WS_FLAGS);
  const int b = blockIdx.x, t = threadIdx.x;
  if      (b <  8) conv_range(w1i, (unsigned short*)(ws+WS_W1I), (b-0)*4096, 32768, flags[1], t);
  else if (b < 24) conv_range(w1h, (unsigned short*)(ws+WS_W1H), (b-8)*4096, 65536, flags[2], t);
  else if (b < 40) conv_range(w2i, (unsigned short*)(ws+WS_W2I), (b-24)*4096, 65536, flags[3], t);
  else if (b < 56) conv_range(w2h, (unsigned short*)(ws+WS_W2H), (b-40)*4096, 65536, flags[4], t);
  else if (b < 62) conv_range(k0,  (unsigned short*)(ws+WS_WK0), (b-56)*4096, 24576, flags[5], t);
  else if (b < 66) conv_range(k1,  (unsigned short*)(ws+WS_WK1), (b-62)*4096, 16384, flags[6], t);
  else if (b < 70) conv_range(k2,  (unsigned short*)(ws+WS_WK2), (b-66)*4096, 16384, flags[7], t);
  else if (b < 74) conv_range(k3,  (unsigned short*)(ws+WS_WK3), (b-70)*4096, 16384, flags[8], t);
  else if (b < 78) conv_range(k4,  (unsigned short*)(ws+WS_WK4), (b-74)*4096, 16384, flags[9], t);
  else if (b < 80) conv_range(k5,  (unsigned short*)(ws+WS_WK5), (b-78)*4096,  8192, flags[10], t);
  else {
    float* b1 = (float*)(ws+WS_B1);
    float* b2 = (float*)(ws+WS_B2);
    for (int i = t; i < 512; i += 256){
      b1[i] = ld1f(bi1, i, flags[1]) + ld1f(bh1, i, flags[2]);
      b2[i] = ld1f(bi2, i, flags[3]) + ld1f(bh2, i, flags[4]);
    }
    const void* bks[6] = {bb0, bb1, bb2, bb3, bb4, bb5};
    const size_t dof[6] = {WS_BK0, WS_BK1, WS_BK2, WS_BK3, WS_BK4, WS_BK5};
    for (int a = 0; a < 6; a++){
      int n = (a == 5) ? 64 : 128;
      float* d = (float*)(ws + dof[a]);
      for (int i = t; i < n; i += 256) d[i] = ld1f(bks[a], i, flags[5+a]);
    }
  }
}

// ---------------------------------------------------------------------------
// LSTM persistent kernel
// ---------------------------------------------------------------------------
__global__ __launch_bounds__(512)
__attribute__((amdgpu_waves_per_eu(2, 2)))
void lstm_kernel(const void* __restrict__ x,
                 const unsigned short* __restrict__ W1I,
                 const unsigned short* __restrict__ W1H,
                 const unsigned short* __restrict__ W2I,
                 const unsigned short* __restrict__ W2H,
                 const float* __restrict__ B1, const float* __restrict__ B2,
                 unsigned short* __restrict__ RB,
                 const int* __restrict__ flags,
                 void* __restrict__ out)
{
  // 131072 + 12800 + 16896 = 160768 B LDS (<= 163840) -> 1 block/CU.
  __shared__ __align__(16) short8 WPARK[8][16][64];          // w1 kc=0..3, all q
  __shared__ __align__(16) unsigned short A1s[2][16][200];   // [x(64)|h1(128)]
  __shared__ __align__(16) unsigned short A2s[2][16][264];   // [h1(128)|h2(128)]

  const int fx = flags[0];
  const int fo = fx;   // output dtype follows x

  const int tid  = threadIdx.x;
  const int w    = tid >> 6;
  const int lane = tid & 63;
  const int l15  = lane & 15;
  const int lq   = lane >> 4;
  const int r0   = blockIdx.x * 16;
  const int mycol = w*16 + l15;
  const int xm = tid >> 5;
  const int xc = (tid & 31) * 2;

  // ---- LDS-parked: w1 kc=0..3 (W1I both halves + W1H kc=0,1), all 4 gates
  #pragma unroll
  for (int q = 0; q < 4; q++){
    const int n = q*128 + mycol;
    WPARK[w][q*4+0][lane] = *(const short8*)(W1I + (size_t)n*64 + lq*8);
    WPARK[w][q*4+1][lane] = *(const short8*)(W1I + (size_t)n*64 + 32 + lq*8);
    WPARK[w][q*4+2][lane] = *(const short8*)(W1H + (size_t)n*128 + lq*8);
    WPARK[w][q*4+3][lane] = *(const short8*)(W1H + (size_t)n*128 + 32 + lq*8);
  }

  // ---- AGPR-resident: w1 kc=4,5 (8 frags) + w2 all q kc=0..7 (32 frags)
  //      = 40 frags = 160 AGPRs, pinned with the "a" constraint so MFMA
  //      reads them directly from AGPR (no per-use moves).
  short8 w1r[4][2];
  #pragma unroll
  for (int q = 0; q < 4; q++){
    const int n = q*128 + mycol;
    #pragma unroll
    for (int i = 0; i < 2; i++)
      w1r[q][i] = *(const short8*)(W1H + (size_t)n*128 + (i+2)*32 + lq*8);
  }
  short8 w2r[4][8];
  #pragma unroll
  for (int q = 0; q < 4; q++){
    const int n = q*128 + mycol;
    #pragma unroll
    for (int kc = 0; kc < 8; kc++){
      const unsigned short* p = (kc < 4) ? (W2I + (size_t)n*128 + kc*32     + lq*8)
                                         : (W2H + (size_t)n*128 + (kc-4)*32 + lq*8);
      w2r[q][kc] = *(const short8*)p;
    }
  }
  // Pin into AGPRs: the allocator must keep these 160 regs resident; MFMA
  // consumes AGPR operands at full rate on gfx950.
  #pragma unroll
  for (int q = 0; q < 4; q++){
    #pragma unroll
    for (int i = 0; i < 2; i++)  asm volatile("" : "+a"(w1r[q][i]));
    #pragma unroll
    for (int kc = 0; kc < 8; kc++) asm volatile("" : "+a"(w2r[q][kc]));
  }

  float b1[4], b2[4];
  #pragma unroll
  for (int q = 0; q < 4; q++){
    b1[q] = B1[q*128 + mycol];
    b2[q] = B2[q*128 + mycol];
  }

  for (int i = tid; i < 16*128; i += 512){
    int m = i >> 7, c = i & 127;
    A1s[0][m][64 + c]  = 0;
    A2s[0][m][128 + c] = 0;
  }
  size_t xoff = ((size_t)(r0 + xm))*256*64 + xc;   // x element offset at t=0
  *(unsigned int*)&A1s[0][xm][xc] = ldx2(x, xoff, fx);

  float c1r[4] = {0.f,0.f,0.f,0.f};
  float c2r[4] = {0.f,0.f,0.f,0.f};
  float h2f[4] = {0.f,0.f,0.f,0.f};
  unsigned short h2b[4] = {0,0,0,0};
  __syncthreads();

  for (int t = 0; t < 256; t++){
    const int buf = t & 1, nbuf = buf ^ 1;

    // prefetch x(t+1) (register load; the only in-loop vmem, so the barrier
    // vmcnt drain only waits on this, with ~a full cell1 of issue distance)
    unsigned int xv = 0u;
    if (t < 255){
      xoff += 64;
      xv = ldx2(x, xoff, fx);
    }

    // ---- cell1: gates = [x_t | h1(t-1)] @ W1^T
    float4v acc[4];
    #pragma unroll
    for (int q = 0; q < 4; q++) acc[q] = (float4v){b1[q], b1[q], b1[q], b1[q]};
    #pragma unroll
    for (int kc = 0; kc < 4; kc++){
      short8 af = *(const short8*)&A1s[buf][l15][kc*32 + lq*8];
      #pragma unroll
      for (int q = 0; q < 4; q++)
        acc[q] = MFMA16(af, WPARK[w][q*4+kc][lane], acc[q]);
    }
    #pragma unroll
    for (int kc = 4; kc < 6; kc++){
      short8 af = *(const short8*)&A1s[buf][l15][kc*32 + lq*8];
      #pragma unroll
      for (int q = 0; q < 4; q++)
        acc[q] = MFMA16(af, w1r[q][kc-4], acc[q]);
    }

    unsigned short h1b[4];
    #pragma unroll
    for (int r = 0; r < 4; r++){
      float ig = sig_(acc[0][r]);
      float fg = sig_(acc[1][r]);
      float gg = tanh_(acc[2][r]);
      float og = sig_(acc[3][r]);
      c1r[r] = fg*c1r[r] + ig*gg;
      h1b[r] = f2bf(og * tanh_(c1r[r]));
    }
    #pragma unroll
    for (int r = 0; r < 4; r++){
      int row = lq*4 + r;
      A2s[buf][row][mycol]       = h1b[r];
      A1s[nbuf][row][64 + mycol] = h1b[r];
    }

    __syncthreads();   // h1(t) visible for cell2

    // ---- cell2: gates = [h1(t) | h2(t-1)] @ W2^T  (fully AGPR-resident)
    #pragma unroll
    for (int q = 0; q < 4; q++) acc[q] = (float4v){b2[q], b2[q], b2[q], b2[q]};
    #pragma unroll
    for (int kc = 0; kc < 8; kc++){
      short8 af = *(const short8*)&A2s[buf][l15][kc*32 + lq*8];
      acc[0] = MFMA16(af, w2r[0][kc], acc[0]);
      acc[1] = MFMA16(af, w2r[1][kc], acc[1]);
      acc[2] = MFMA16(af, w2r[2][kc], acc[2]);
      acc[3] = MFMA16(af, w2r[3][kc], acc[3]);
    }

    #pragma unroll
    for (int r = 0; r < 4; r++){
      float ig = sig_(acc[0][r]);
      float fg = sig_(acc[1][r]);
      float gg = tanh_(acc[2][r]);
      float og = sig_(acc[3][r]);
      c2r[r] = fg*c2r[r] + ig*gg;
      h2f[r] = og * tanh_(c2r[r]);
      h2b[r] = f2bf(h2f[r]);
    }
    #pragma unroll
    for (int r = 0; r < 4; r++){
      int row = lq*4 + r;
      A2s[nbuf][row][128 + mycol] = h2b[r];
    }
    if (t < 255)
      *(unsigned int*)&A1s[nbuf][xm][xc] = xv;
    __syncthreads();
  }

  // ---- epilogue: h2(T-1) outputs + r tail (x[:,255,:])
  #pragma unroll
  for (int r = 0; r < 4; r++){
    size_t grow = (size_t)(r0 + lq*4 + r);
    st1(out, OFF_H2 + grow*128 + mycol, h2f[r], fo);
    st1(out, OFF_R  + grow*192 + mycol, h2f[r], fo);
    RB[grow*192 + mycol] = h2b[r];
  }
  {
    // xoff now points at t=255 for this thread's (row, xc) pair
    float v0, v1;
    if (fx){ const float* p = (const float*)x + xoff; v0 = p[0]; v1 = p[1]; }
    else   { const unsigned short* p = (const unsigned short*)x + xoff;
             v0 = bf2f(p[0]); v1 = bf2f(p[1]); }
    size_t rrow = (size_t)(r0 + xm)*192 + 128 + xc;
    st1(out, OFF_R + rrow,     v0, fo);
    st1(out, OFF_R + rrow + 1, v1, fo);
    RB[rrow]     = f2bf(v0);
    RB[rrow + 1] = f2bf(v1);
  }
}

// ---------------------------------------------------------------------------
// KDN with MFMA: r[2048,192] -> 128 x5 (ReLU) -> 64
// ---------------------------------------------------------------------------
__global__ __launch_bounds__(256)
void kdn_kernel(const char* __restrict__ ws, void* __restrict__ out)
{
  __shared__ __align__(16) unsigned short bufA[16][200];
  __shared__ __align__(16) unsigned short bufB[16][200];

  const int* flags = (const int*)(ws + WS_FLAGS);
  const int fo = flags[0];

  const int tid = threadIdx.x;
  const int w    = tid >> 6;
  const int lane = tid & 63;
  const int l15  = lane & 15;
  const int lq   = lane >> 4;
  const int r0  = blockIdx.x * 16;

  const unsigned short* RB = (const unsigned short*)(ws + WS_RB);

  for (int i = tid; i < 1536; i += 256){
    int row = i / 96, c2 = (i % 96) * 2;
    *(unsigned int*)&bufA[row][c2] =
        *(const unsigned int*)&RB[(size_t)(r0 + row)*192 + c2];
  }
  __syncthreads();

  const unsigned short* WK[6] = {
    (const unsigned short*)(ws+WS_WK0), (const unsigned short*)(ws+WS_WK1),
    (const unsigned short*)(ws+WS_WK2), (const unsigned short*)(ws+WS_WK3),
    (const unsigned short*)(ws+WS_WK4), (const unsigned short*)(ws+WS_WK5)};
  const float* BK[6] = {
    (const float*)(ws+WS_BK0), (const float*)(ws+WS_BK1),
    (const float*)(ws+WS_BK2), (const float*)(ws+WS_BK3),
    (const float*)(ws+WS_BK4), (const float*)(ws+WS_BK5)};

  unsigned short (*src)[200] = bufA;
  unsigned short (*dst)[200] = bufB;

  #pragma unroll
  for (int l = 0; l < 5; l++){
    const int K = (l == 0) ? 192 : 128;
    const int nk = K / 32;
    #pragma unroll
    for (int tau = 0; tau < 2; tau++){
      const int n = w*32 + tau*16 + l15;
      float bv = BK[l][n];
      float4v acc = {bv, bv, bv, bv};
      for (int kc = 0; kc < nk; kc++){
        short8 af = *(const short8*)&src[l15][kc*32 + lq*8];
        short8 wf = *(const short8*)(WK[l] + (size_t)n*K + kc*32 + lq*8);
        acc = MFMA16(af, wf, acc);
      }
      #pragma unroll
      for (int r = 0; r < 4; r++)
        dst[lq*4 + r][n] = f2bf(fmaxf(acc[r], 0.0f));
    }
    __syncthreads();
    unsigned short (*tmp)[200] = src; src = dst; dst = tmp;
  }

  {
    const int n = w*16 + l15;
    float bv = BK[5][n];
    float4v acc = {bv, bv, bv, bv};
    #pragma unroll
    for (int kc = 0; kc < 4; kc++){
      short8 af = *(const short8*)&src[l15][kc*32 + lq*8];
      short8 wf = *(const short8*)(WK[5] + (size_t)n*128 + kc*32 + lq*8);
      acc = MFMA16(af, wf, acc);
    }
    #pragma unroll
    for (int r = 0; r < 4; r++)
      st1(out, OFF_Y + (size_t)(r0 + lq*4 + r)*64 + n, acc[r], fo);
  }
}

// ---------------------------------------------------------------------------
extern "C" void kernel_launch(void* const* d_in, const int* in_sizes, int n_in,
                              void* d_out, int out_size, void* d_ws, size_t ws_size,
                              hipStream_t stream)
{
  (void)in_sizes; (void)n_in; (void)ws_size; (void)out_size;

  const void* x    = d_in[0];
  const void* Wih1 = d_in[1];
  const void* Whh1 = d_in[2];
  const void* bih1 = d_in[3];
  const void* bhh1 = d_in[4];
  const void* Wih2 = d_in[5];
  const void* Whh2 = d_in[6];
  const void* bih2 = d_in[7];
  const void* bhh2 = d_in[8];
  const void* Wk0 = d_in[9];  const void* bk0 = d_in[10];
  const void* Wk1 = d_in[11]; const void* bk1 = d_in[12];
  const void* Wk2 = d_in[13]; const void* bk2 = d_in[14];
  const void* Wk3 = d_in[15]; const void* bk3 = d_in[16];
  const void* Wk4 = d_in[17]; const void* bk4 = d_in[18];
  const void* Wk5 = d_in[19]; const void* bk5 = d_in[20];

  char* ws = (char*)d_ws;

  hipLaunchKernelGGL(probe_kernel, dim3(1), dim3(64), 0, stream,
                     x, Wih1, Whh1, Wih2, Whh2,
                     Wk0, Wk1, Wk2, Wk3, Wk4, Wk5, (int*)(ws + WS_FLAGS));
  hipLaunchKernelGGL(convert_kernel, dim3(81), dim3(256), 0, stream,
                     Wih1, Whh1, Wih2, Whh2,
                     Wk0, Wk1, Wk2, Wk3, Wk4, Wk5,
                     bih1, bhh1, bih2, bhh2,
                     bk0, bk1, bk2, bk3, bk4, bk5, ws);
  hipLaunchKernelGGL(lstm_kernel, dim3(128), dim3(512), 0, stream,
                     x,
                     (const unsigned short*)(ws + WS_W1I),
                     (const unsigned short*)(ws + WS_W1H),
                     (const unsigned short*)(ws + WS_W2I),
                     (const unsigned short*)(ws + WS_W2H),
                     (const float*)(ws + WS_B1), (const float*)(ws + WS_B2),
                     (unsigned short*)(ws + WS_RB),
                     (const int*)(ws + WS_FLAGS),
                     d_out);
  hipLaunchKernelGGL(kdn_kernel, dim3(128), dim3(256), 0, stream,
                     ws, d_out);
}

// Round 3
// 962.167 us; speedup vs baseline: 1.4578x; 1.4578x over previous
//
#include <hip/hip_runtime.h>
#include <cstddef>

// DFMNET: 2-layer LSTM (B=2048,T=256,I=64,H=128) + 6-layer KDN.
// Round 8: r6's "+v" pin DID work (weights AGPR-resident via live-range split;
// arch VGPR=128 is expected); r7's "+a" regressed (forced alloc conflicts).
// Remaining bottleneck per counters: (a) IEEE divides in sigmoid/tanh (~9
// instr each, 40/thread/step), (b) per-step vmcnt(0) drain at barriers on the
// cold-HBM x prefetch (~900 cy/step), (c) 2-barrier lockstep = trans pipe and
// MFMA pipe never overlap. Fix: raw v_rcp/v_exp; rotated ONE-barrier pipeline
// { mfma2(t) || mfma1(t+1) ; act2(t) || act1(t+1) ; writes ; barrier }; 3-deep
// x prefetch issued inside the compute block.

typedef __attribute__((ext_vector_type(8))) short short8;
typedef __attribute__((ext_vector_type(4))) float float4v;

#define OFF_Y  ((size_t)0)
#define OFF_H2 ((size_t)2048*64)
#define OFF_R  ((size_t)2048*192)

// ---- d_ws byte offsets (all 64-aligned) ----
#define WS_FLAGS   0
#define WS_W1I     64           // [512][64]  bf16
#define WS_W1H     65600        // [512][128] bf16
#define WS_W2I     196672      // [512][128] bf16
#define WS_W2H     327744      // [512][128] bf16
#define WS_WK0     458816      // [128][192] bf16
#define WS_WK1     507968      // [128][128] bf16
#define WS_WK2     540736
#define WS_WK3     573504
#define WS_WK4     606272
#define WS_WK5     639040      // [64][128] bf16
#define WS_B1      655424      // [512] f32 (bih1+bhh1)
#define WS_B2      657472      // [512] f32
#define WS_BK0     659520      // [128] f32
#define WS_BK1     660032
#define WS_BK2     660544
#define WS_BK3     661056
#define WS_BK4     661568
#define WS_BK5     662080      // [64] f32
#define WS_RB      662336      // [2048][192] bf16

__device__ __forceinline__ float bf2f(unsigned short u){
  union { unsigned int i; float f; } c; c.i = ((unsigned int)u) << 16; return c.f;
}
__device__ __forceinline__ unsigned short f2bf(float f){
  union { float f; unsigned int i; } c; c.f = f;
  unsigned int x = c.i;
  unsigned int r = (x + 0x7FFFu + ((x >> 16) & 1u)) >> 16;   // RNE
  return (unsigned short)r;
}

// Raw transcendentals: v_exp_f32 (2^x) + v_rcp_f32, no IEEE-div expansion.
__device__ __forceinline__ float exp2_(float x){
  float r; asm("v_exp_f32 %0, %1" : "=v"(r) : "v"(x)); return r;
}
__device__ __forceinline__ float rcp_(float x){
  float r; asm("v_rcp_f32 %0, %1" : "=v"(r) : "v"(x)); return r;
}
#define LOG2E 1.442695041f
__device__ __forceinline__ float sig_(float x){
  return rcp_(1.0f + exp2_(-LOG2E * x));
}
__device__ __forceinline__ float tanh_(float x){
  return 2.0f * rcp_(1.0f + exp2_(-2.0f*LOG2E * x)) - 1.0f;
}

#define MFMA16(a,b,c) __builtin_amdgcn_mfma_f32_16x16x32_bf16((a),(b),(c),0,0,0)

__device__ __forceinline__ unsigned int ldx2(const void* x, size_t off, int f32){
  if (f32){
    const float* p = (const float*)x + off;
    return (unsigned int)f2bf(p[0]) | ((unsigned int)f2bf(p[1]) << 16);
  }
  return *(const unsigned int*)((const unsigned short*)x + off);
}
__device__ __forceinline__ float ld1f(const void* p, int i, int f32){
  if (f32) return ((const float*)p)[i];
  return bf2f(((const unsigned short*)p)[i]);
}
__device__ __forceinline__ void st1(void* o, size_t off, float v, int f32){
  if (f32) ((float*)o)[off] = v;
  else     ((unsigned short*)o)[off] = f2bf(v);
}

// gate activations for one cell (4 rows/lane)
__device__ __forceinline__ void act_cell(const float4v acc[4], float cr[4],
                                         unsigned short hb[4], float hf[4]){
  #pragma unroll
  for (int r = 0; r < 4; r++){
    float ig = sig_(acc[0][r]);
    float fg = sig_(acc[1][r]);
    float gg = tanh_(acc[2][r]);
    float og = sig_(acc[3][r]);
    cr[r] = fg*cr[r] + ig*gg;
    float h = og * tanh_(cr[r]);
    hf[r] = h;
    hb[r] = f2bf(h);
  }
}

// ---------------------------------------------------------------------------
// dtype probe: flags[a]=1 iff array a is fp32 (verified round 3)
// ---------------------------------------------------------------------------
__global__ void probe_kernel(const void* x,
                             const void* w1i, const void* w1h,
                             const void* w2i, const void* w2h,
                             const void* k0, const void* k1, const void* k2,
                             const void* k3, const void* k4, const void* k5,
                             int* flags)
{
  const void* arrs[11] = {x, w1i, w1h, w2i, w2h, k0, k1, k2, k3, k4, k5};
  const int lane = threadIdx.x & 63;
  for (int a = 0; a < 11; a++){
    const unsigned short* p = (const unsigned short*)arrs[a];
    int bad = 0;
    #pragma unroll
    for (int j = 0; j < 8; j++){
      float v = bf2f(p[lane*8 + j]);
      if (!(v > -1e3f && v < 1e3f)) bad = 1;
    }
    unsigned long long m = __ballot(bad);
    if (lane == 0) flags[a] = (m != 0ull) ? 1 : 0;
  }
}

// ---------------------------------------------------------------------------
// convert: weights -> bf16 in ws; bias sums -> f32 in ws
// ---------------------------------------------------------------------------
__device__ __forceinline__ void conv_range(const void* src, unsigned short* dst,
                                           int lo, int n, int f32, int t){
  int hi = lo + 4096; if (hi > n) hi = n;
  for (int i = lo + t; i < hi; i += 256)
    dst[i] = f32 ? f2bf(((const float*)src)[i]) : ((const unsigned short*)src)[i];
}

__global__ void convert_kernel(const void* w1i, const void* w1h,
                               const void* w2i, const void* w2h,
                               const void* k0, const void* k1, const void* k2,
                               const void* k3, const void* k4, const void* k5,
                               const void* bi1, const void* bh1,
                               const void* bi2, const void* bh2,
                               const void* bb0, const void* bb1, const void* bb2,
                               const void* bb3, const void* bb4, const void* bb5,
                               char* ws)
{
  const int* flags = (const int*)(ws + WS_FLAGS);
  const int b = blockIdx.x, t = threadIdx.x;
  if      (b <  8) conv_range(w1i, (unsigned short*)(ws+WS_W1I), (b-0)*4096, 32768, flags[1], t);
  else if (b < 24) conv_range(w1h, (unsigned short*)(ws+WS_W1H), (b-8)*4096, 65536, flags[2], t);
  else if (b < 40) conv_range(w2i, (unsigned short*)(ws+WS_W2I), (b-24)*4096, 65536, flags[3], t);
  else if (b < 56) conv_range(w2h, (unsigned short*)(ws+WS_W2H), (b-40)*4096, 65536, flags[4], t);
  else if (b < 62) conv_range(k0,  (unsigned short*)(ws+WS_WK0), (b-56)*4096, 24576, flags[5], t);
  else if (b < 66) conv_range(k1,  (unsigned short*)(ws+WS_WK1), (b-62)*4096, 16384, flags[6], t);
  else if (b < 70) conv_range(k2,  (unsigned short*)(ws+WS_WK2), (b-66)*4096, 16384, flags[7], t);
  else if (b < 74) conv_range(k3,  (unsigned short*)(ws+WS_WK3), (b-70)*4096, 16384, flags[8], t);
  else if (b < 78) conv_range(k4,  (unsigned short*)(ws+WS_WK4), (b-74)*4096, 16384, flags[9], t);
  else if (b < 80) conv_range(k5,  (unsigned short*)(ws+WS_WK5), (b-78)*4096,  8192, flags[10], t);
  else {
    float* b1 = (float*)(ws+WS_B1);
    float* b2 = (float*)(ws+WS_B2);
    for (int i = t; i < 512; i += 256){
      b1[i] = ld1f(bi1, i, flags[1]) + ld1f(bh1, i, flags[2]);
      b2[i] = ld1f(bi2, i, flags[3]) + ld1f(bh2, i, flags[4]);
    }
    const void* bks[6] = {bb0, bb1, bb2, bb3, bb4, bb5};
    const size_t dof[6] = {WS_BK0, WS_BK1, WS_BK2, WS_BK3, WS_BK4, WS_BK5};
    for (int a = 0; a < 6; a++){
      int n = (a == 5) ? 64 : 128;
      float* d = (float*)(ws + dof[a]);
      for (int i = t; i < n; i += 256) d[i] = ld1f(bks[a], i, flags[5+a]);
    }
  }
}

// ---------------------------------------------------------------------------
// LSTM persistent kernel — rotated 1-barrier/step pipeline
// ---------------------------------------------------------------------------
__global__ __launch_bounds__(512)
__attribute__((amdgpu_waves_per_eu(2, 2)))
void lstm_kernel(const void* __restrict__ x,
                 const unsigned short* __restrict__ W1I,
                 const unsigned short* __restrict__ W1H,
                 const unsigned short* __restrict__ W2I,
                 const unsigned short* __restrict__ W2H,
                 const float* __restrict__ B1, const float* __restrict__ B2,
                 unsigned short* __restrict__ RB,
                 const int* __restrict__ flags,
                 void* __restrict__ out)
{
  // 131072 + 12800 + 16896 = 160768 B LDS (<= 163840) -> 1 block/CU.
  __shared__ __align__(16) short8 WPARK[8][16][64];          // w1 kc=0..3, all q
  __shared__ __align__(16) unsigned short A1s[2][16][200];   // [x(64)|h1(128)]
  __shared__ __align__(16) unsigned short A2s[2][16][264];   // [h1(128)|h2(128)]

  const int fx = flags[0];
  const int fo = fx;   // output dtype follows x

  const int tid  = threadIdx.x;
  const int w    = tid >> 6;
  const int lane = tid & 63;
  const int l15  = lane & 15;
  const int lq   = lane >> 4;
  const int r0   = blockIdx.x * 16;
  const int mycol = w*16 + l15;
  const int xm = tid >> 5;
  const int xc = (tid & 31) * 2;

  // ---- LDS-parked: w1 kc=0..3 (W1I both halves + W1H kc=0,1), all 4 gates
  #pragma unroll
  for (int q = 0; q < 4; q++){
    const int n = q*128 + mycol;
    WPARK[w][q*4+0][lane] = *(const short8*)(W1I + (size_t)n*64 + lq*8);
    WPARK[w][q*4+1][lane] = *(const short8*)(W1I + (size_t)n*64 + 32 + lq*8);
    WPARK[w][q*4+2][lane] = *(const short8*)(W1H + (size_t)n*128 + lq*8);
    WPARK[w][q*4+3][lane] = *(const short8*)(W1H + (size_t)n*128 + 32 + lq*8);
  }

  // ---- resident: w1 kc=4,5 (8 frags) + w2 all q kc=0..7 (32 frags) = 40
  //      frags = 160 regs; "+v" pin (r6-style — compiler shunts to AGPRs and
  //      MFMA reads them there directly; do NOT use "+a", r7 regression).
  short8 w1r[4][2];
  #pragma unroll
  for (int q = 0; q < 4; q++){
    const int n = q*128 + mycol;
    #pragma unroll
    for (int i = 0; i < 2; i++)
      w1r[q][i] = *(const short8*)(W1H + (size_t)n*128 + (i+2)*32 + lq*8);
  }
  short8 w2r[4][8];
  #pragma unroll
  for (int q = 0; q < 4; q++){
    const int n = q*128 + mycol;
    #pragma unroll
    for (int kc = 0; kc < 8; kc++){
      const unsigned short* p = (kc < 4) ? (W2I + (size_t)n*128 + kc*32     + lq*8)
                                         : (W2H + (size_t)n*128 + (kc-4)*32 + lq*8);
      w2r[q][kc] = *(const short8*)p;
    }
  }
  #pragma unroll
  for (int q = 0; q < 4; q++){
    #pragma unroll
    for (int i = 0; i < 2; i++)  asm volatile("" : "+v"(w1r[q][i]));
    #pragma unroll
    for (int kc = 0; kc < 8; kc++) asm volatile("" : "+v"(w2r[q][kc]));
  }

  float b1[4], b2[4];
  #pragma unroll
  for (int q = 0; q < 4; q++){
    b1[q] = B1[q*128 + mycol];
    b2[q] = B2[q*128 + mycol];
  }

  // zero h1-region of A1s[0] and h2-region of A2s[0]
  for (int i = tid; i < 16*128; i += 512){
    int m = i >> 7, c = i & 127;
    A1s[0][m][64 + c]  = 0;
    A2s[0][m][128 + c] = 0;
  }
  // x pipeline: x(0) -> LDS; x(1),x(2) -> regs; xoff tracks last-loaded t.
  size_t xoff = ((size_t)(r0 + xm))*256*64 + xc;
  *(unsigned int*)&A1s[0][xm][xc] = ldx2(x, xoff, fx);
  unsigned int xv1 = ldx2(x, xoff + 64,  fx);   // x(1)
  unsigned int xv_c = ldx2(x, xoff + 128, fx);  // x(2)
  xoff += 128;

  float c1r[4] = {0.f,0.f,0.f,0.f};
  float c2r[4] = {0.f,0.f,0.f,0.f};
  float h2f[4] = {0.f,0.f,0.f,0.f};
  unsigned short h2b[4] = {0,0,0,0};
  __syncthreads();

  // ---- prologue: mfma1(0) + act1(0); h1(0) -> A2s[0] + A1s[1]; x(1) -> A1s[1]
  {
    float4v acc1[4];
    #pragma unroll
    for (int q = 0; q < 4; q++) acc1[q] = (float4v){b1[q], b1[q], b1[q], b1[q]};
    #pragma unroll
    for (int kc = 0; kc < 4; kc++){
      short8 af = *(const short8*)&A1s[0][l15][kc*32 + lq*8];
      #pragma unroll
      for (int q = 0; q < 4; q++)
        acc1[q] = MFMA16(af, WPARK[w][q*4+kc][lane], acc1[q]);
    }
    #pragma unroll
    for (int kc = 4; kc < 6; kc++){
      short8 af = *(const short8*)&A1s[0][l15][kc*32 + lq*8];
      #pragma unroll
      for (int q = 0; q < 4; q++)
        acc1[q] = MFMA16(af, w1r[q][kc-4], acc1[q]);
    }
    float h1f[4]; unsigned short h1b[4];
    act_cell(acc1, c1r, h1b, h1f);
    #pragma unroll
    for (int r = 0; r < 4; r++){
      int row = lq*4 + r;
      A2s[0][row][mycol]      = h1b[r];
      A1s[1][row][64 + mycol] = h1b[r];
    }
    *(unsigned int*)&A1s[1][xm][xc] = xv1;
  }
  __syncthreads();

  // ---- main loop: ONE barrier per step.
  //  iter t: mfma2(t) [A2s[t&1]]  ||  mfma1(t+1) [A1s[(t&1)^1]]
  //          act2(t) -> h2 -> A2s[(t&1)^1]
  //          act1(t+1) -> h1 -> A2s[(t&1)^1], A1s[t&1]; x(t+2) -> A1s[t&1]
  for (int t = 0; t < 256; t++){
    const int rA = t & 1;          // A2s read buf; A1s write buf
    const int rB = rA ^ 1;         // A1s read buf; A2s write buf

    // issue x(t+3) (consumed as xv_c two iterations from now; the barrier
    // vmcnt drain sees a load issued a full body earlier)
    unsigned int xv_n = 0u;
    if (t < 253){
      xoff += 64;
      xv_n = ldx2(x, xoff, fx);
    }

    // ---- mfma2(t): gates2 = [h1(t) | h2(t-1)] @ W2^T
    float4v acc2[4];
    #pragma unroll
    for (int q = 0; q < 4; q++) acc2[q] = (float4v){b2[q], b2[q], b2[q], b2[q]};
    #pragma unroll
    for (int kc = 0; kc < 8; kc++){
      short8 af = *(const short8*)&A2s[rA][l15][kc*32 + lq*8];
      acc2[0] = MFMA16(af, w2r[0][kc], acc2[0]);
      acc2[1] = MFMA16(af, w2r[1][kc], acc2[1]);
      acc2[2] = MFMA16(af, w2r[2][kc], acc2[2]);
      acc2[3] = MFMA16(af, w2r[3][kc], acc2[3]);
    }

    if (t < 255){
      // ---- mfma1(t+1): gates1 = [x(t+1) | h1(t)] @ W1^T  (independent of acc2)
      float4v acc1[4];
      #pragma unroll
      for (int q = 0; q < 4; q++) acc1[q] = (float4v){b1[q], b1[q], b1[q], b1[q]};
      #pragma unroll
      for (int kc = 0; kc < 4; kc++){
        short8 af = *(const short8*)&A1s[rB][l15][kc*32 + lq*8];
        #pragma unroll
        for (int q = 0; q < 4; q++)
          acc1[q] = MFMA16(af, WPARK[w][q*4+kc][lane], acc1[q]);
      }
      #pragma unroll
      for (int kc = 4; kc < 6; kc++){
        short8 af = *(const short8*)&A1s[rB][l15][kc*32 + lq*8];
        #pragma unroll
        for (int q = 0; q < 4; q++)
          acc1[q] = MFMA16(af, w1r[q][kc-4], acc1[q]);
      }

      // ---- act2(t)
      act_cell(acc2, c2r, h2b, h2f);
      #pragma unroll
      for (int r = 0; r < 4; r++)
        A2s[rB][lq*4 + r][128 + mycol] = h2b[r];

      // ---- act1(t+1)
      float h1f[4]; unsigned short h1b[4];
      act_cell(acc1, c1r, h1b, h1f);
      #pragma unroll
      for (int r = 0; r < 4; r++){
        int row = lq*4 + r;
        A2s[rB][row][mycol]      = h1b[r];
        A1s[rA][row][64 + mycol] = h1b[r];
      }
      *(unsigned int*)&A1s[rA][xm][xc] = xv_c;   // x(t+2)
      xv_c = xv_n;
    } else {
      // final step: only act2(255)
      act_cell(acc2, c2r, h2b, h2f);
    }
    __syncthreads();
  }

  // ---- epilogue: h2(T-1) outputs + r tail (x[:,255,:])
  #pragma unroll
  for (int r = 0; r < 4; r++){
    size_t grow = (size_t)(r0 + lq*4 + r);
    st1(out, OFF_H2 + grow*128 + mycol, h2f[r], fo);
    st1(out, OFF_R  + grow*192 + mycol, h2f[r], fo);
    RB[grow*192 + mycol] = h2b[r];
  }
  {
    // xoff advanced 253 times from x(2) -> points at x(255)
    float v0, v1;
    if (fx){ const float* p = (const float*)x + xoff; v0 = p[0]; v1 = p[1]; }
    else   { const unsigned short* p = (const unsigned short*)x + xoff;
             v0 = bf2f(p[0]); v1 = bf2f(p[1]); }
    size_t rrow = (size_t)(r0 + xm)*192 + 128 + xc;
    st1(out, OFF_R + rrow,     v0, fo);
    st1(out, OFF_R + rrow + 1, v1, fo);
    RB[rrow]     = f2bf(v0);
    RB[rrow + 1] = f2bf(v1);
  }
}

// ---------------------------------------------------------------------------
// KDN with MFMA: r[2048,192] -> 128 x5 (ReLU) -> 64
// ---------------------------------------------------------------------------
__global__ __launch_bounds__(256)
void kdn_kernel(const char* __restrict__ ws, void* __restrict__ out)
{
  __shared__ __align__(16) unsigned short bufA[16][200];
  __shared__ __align__(16) unsigned short bufB[16][200];

  const int* flags = (const int*)(ws + WS_FLAGS);
  const int fo = flags[0];

  const int tid = threadIdx.x;
  const int w    = tid >> 6;
  const int lane = tid & 63;
  const int l15  = lane & 15;
  const int lq   = lane >> 4;
  const int r0  = blockIdx.x * 16;

  const unsigned short* RB = (const unsigned short*)(ws + WS_RB);

  for (int i = tid; i < 1536; i += 256){
    int row = i / 96, c2 = (i % 96) * 2;
    *(unsigned int*)&bufA[row][c2] =
        *(const unsigned int*)&RB[(size_t)(r0 + row)*192 + c2];
  }
  __syncthreads();

  const unsigned short* WK[6] = {
    (const unsigned short*)(ws+WS_WK0), (const unsigned short*)(ws+WS_WK1),
    (const unsigned short*)(ws+WS_WK2), (const unsigned short*)(ws+WS_WK3),
    (const unsigned short*)(ws+WS_WK4), (const unsigned short*)(ws+WS_WK5)};
  const float* BK[6] = {
    (const float*)(ws+WS_BK0), (const float*)(ws+WS_BK1),
    (const float*)(ws+WS_BK2), (const float*)(ws+WS_BK3),
    (const float*)(ws+WS_BK4), (const float*)(ws+WS_BK5)};

  unsigned short (*src)[200] = bufA;
  unsigned short (*dst)[200] = bufB;

  #pragma unroll
  for (int l = 0; l < 5; l++){
    const int K = (l == 0) ? 192 : 128;
    const int nk = K / 32;
    #pragma unroll
    for (int tau = 0; tau < 2; tau++){
      const int n = w*32 + tau*16 + l15;
      float bv = BK[l][n];
      float4v acc = {bv, bv, bv, bv};
      for (int kc = 0; kc < nk; kc++){
        short8 af = *(const short8*)&src[l15][kc*32 + lq*8];
        short8 wf = *(const short8*)(WK[l] + (size_t)n*K + kc*32 + lq*8);
        acc = MFMA16(af, wf, acc);
      }
      #pragma unroll
      for (int r = 0; r < 4; r++)
        dst[lq*4 + r][n] = f2bf(fmaxf(acc[r], 0.0f));
    }
    __syncthreads();
    unsigned short (*tmp)[200] = src; src = dst; dst = tmp;
  }

  {
    const int n = w*16 + l15;
    float bv = BK[5][n];
    float4v acc = {bv, bv, bv, bv};
    #pragma unroll
    for (int kc = 0; kc < 4; kc++){
      short8 af = *(const short8*)&src[l15][kc*32 + lq*8];
      short8 wf = *(const short8*)(WK[5] + (size_t)n*128 + kc*32 + lq*8);
      acc = MFMA16(af, wf, acc);
    }
    #pragma unroll
    for (int r = 0; r < 4; r++)
      st1(out, OFF_Y + (size_t)(r0 + lq*4 + r)*64 + n, acc[r], fo);
  }
}

// ---------------------------------------------------------------------------
extern "C" void kernel_launch(void* const* d_in, const int* in_sizes, int n_in,
                              void* d_out, int out_size, void* d_ws, size_t ws_size,
                              hipStream_t stream)
{
  (void)in_sizes; (void)n_in; (void)ws_size; (void)out_size;

  const void* x    = d_in[0];
  const void* Wih1 = d_in[1];
  const void* Whh1 = d_in[2];
  const void* bih1 = d_in[3];
  const void* bhh1 = d_in[4];
  const void* Wih2 = d_in[5];
  const void* Whh2 = d_in[6];
  const void* bih2 = d_in[7];
  const void* bhh2 = d_in[8];
  const void* Wk0 = d_in[9];  const void* bk0 = d_in[10];
  const void* Wk1 = d_in[11]; const void* bk1 = d_in[12];
  const void* Wk2 = d_in[13]; const void* bk2 = d_in[14];
  const void* Wk3 = d_in[15]; const void* bk3 = d_in[16];
  const void* Wk4 = d_in[17]; const void* bk4 = d_in[18];
  const void* Wk5 = d_in[19]; const void* bk5 = d_in[20];

  char* ws = (char*)d_ws;

  hipLaunchKernelGGL(probe_kernel, dim3(1), dim3(64), 0, stream,
                     x, Wih1, Whh1, Wih2, Whh2,
                     Wk0, Wk1, Wk2, Wk3, Wk4, Wk5, (int*)(ws + WS_FLAGS));
  hipLaunchKernelGGL(convert_kernel, dim3(81), dim3(256), 0, stream,
                     Wih1, Whh1, Wih2, Whh2,
                     Wk0, Wk1, Wk2, Wk3, Wk4, Wk5,
                     bih1, bhh1, bih2, bhh2,
                     bk0, bk1, bk2, bk3, bk4, bk5, ws);
  hipLaunchKernelGGL(lstm_kernel, dim3(128), dim3(512), 0, stream,
                     x,
                     (const unsigned short*)(ws + WS_W1I),
                     (const unsigned short*)(ws + WS_W1H),
                     (const unsigned short*)(ws + WS_W2I),
                     (const unsigned short*)(ws + WS_W2H),
                     (const float*)(ws + WS_B1), (const float*)(ws + WS_B2),
                     (unsigned short*)(ws + WS_RB),
                     (const int*)(ws + WS_FLAGS),
                     d_out);
  hipLaunchKernelGGL(kdn_kernel, dim3(128), dim3(256), 0, stream,
                     ws, d_out);
}